// Round 1
// baseline (81.665 us; speedup 1.0000x reference)
//
#include <hip/hip_runtime.h>
#include <hip/hip_fp16.h>

#define TK   65536
#define CDIM 512
#define NDIM 512
#define BM   128

typedef _Float16 half8  __attribute__((ext_vector_type(8)));
typedef _Float16 half4v __attribute__((ext_vector_type(4)));
typedef float    f32x16 __attribute__((ext_vector_type(16)));

// ---------------- K1a: v[j] = relu(Q . Wq[j,:] + bq[j]) * Wout[j/64] / 8 ----------------
__global__ void qproj_kernel(const float* __restrict__ Q, const float* __restrict__ Wq,
                             const float* __restrict__ bq, const float* __restrict__ Wout,
                             float* __restrict__ v) {
    __shared__ float qs[CDIM];
    const int t = threadIdx.x;
    for (int i = t; i < CDIM; i += 64) qs[i] = Q[i];
    __syncthreads();
    const int j = blockIdx.x * 64 + t;
    const float4* w4 = (const float4*)(Wq + (size_t)j * CDIM);
    const float4* q4 = (const float4*)qs;
    float s = 0.f;
    #pragma unroll 8
    for (int i = 0; i < CDIM / 4; ++i) {
        float4 w = w4[i]; float4 q = q4[i];
        s = fmaf(w.x, q.x, s); s = fmaf(w.y, q.y, s);
        s = fmaf(w.z, q.z, s); s = fmaf(w.w, q.w, s);
    }
    s += bq[j];
    s = fmaxf(s, 0.f);
    v[j] = s * Wout[j >> 6] * 0.125f;   // 1/sqrt(64) folded in; bout dropped (softmax shift-invariant)
}

// ---------------- K1b: Wk fp32 -> fp16 ----------------
__global__ void wkconv_kernel(const float* __restrict__ Wk, _Float16* __restrict__ Wk16) {
    const int i = (blockIdx.x * 256 + threadIdx.x) * 4;
    float4 w = *(const float4*)(Wk + i);
    half4v h = { (_Float16)w.x, (_Float16)w.y, (_Float16)w.z, (_Float16)w.w };
    *(half4v*)(Wk16 + i) = h;
}

// ---------------- K2: logits[t] = sum_j v[j] * relu(K[t,:] . Wk[j,:] + bk[j]) ----------------
// 4 waves x 32 rows = BM 128 rows/WG. A (K rows) in registers, full K=512, fp16.
// Wk fp16 streamed per-phase (64j x 64k = 8KB) through XOR-swizzled double-buffered LDS.
__global__ __launch_bounds__(256, 2) void score_kernel(
    const float* __restrict__ Kmat, const _Float16* __restrict__ Wk16,
    const float* __restrict__ bk, const float* __restrict__ v,
    float* __restrict__ logits)
{
    __shared__ alignas(16) char lds[2][64 * 128];   // 2 x 8KB
    const int tid  = threadIdx.x;
    const int lane = tid & 63;
    const int wave = tid >> 6;
    const int l31  = lane & 31;
    const int lhi  = lane >> 5;
    const int row  = blockIdx.x * BM + wave * 32 + l31;

    // ---- A prologue: 32 half8 fragments (rows of K, full depth 512) ----
    // 32x32x16 A-fragment: lane holds row (lane&31), k = (lane>>5)*8 + 0..7 of each 16-chunk.
    half8 a[32];
    const float* abase = Kmat + (size_t)row * CDIM + lhi * 8;
    #pragma unroll
    for (int kt = 0; kt < 32; ++kt) {
        float4 f0 = *(const float4*)(abase + kt * 16);
        float4 f1 = *(const float4*)(abase + kt * 16 + 4);
        half8 h;
        h[0] = (_Float16)f0.x; h[1] = (_Float16)f0.y; h[2] = (_Float16)f0.z; h[3] = (_Float16)f0.w;
        h[4] = (_Float16)f1.x; h[5] = (_Float16)f1.y; h[6] = (_Float16)f1.z; h[7] = (_Float16)f1.w;
        a[kt] = h;
    }

    // staging geometry: 256 threads x 32B = 8KB tile; row sj, chunk pair scp
    const int sj  = tid >> 2;           // 0..63 tile row (j within tile)
    const int scp = tid & 3;            // 0..3  (two 16B chunks each)
    const int sw0 = (2 * scp)     ^ (sj & 7);   // swizzled 16B-chunk positions
    const int sw1 = (2 * scp + 1) ^ (sj & 7);

    f32x16 acc[2];
    float part[16];
    #pragma unroll
    for (int f = 0; f < 2; ++f)
        #pragma unroll
        for (int r = 0; r < 16; ++r) acc[f][r] = 0.f;
    #pragma unroll
    for (int r = 0; r < 16; ++r) part[r] = 0.f;

    // prologue: stage tile (jt=0,kq=0) into buf 0
    {
        const _Float16* src = Wk16 + (size_t)sj * NDIM + scp * 16;
        uint4 s0 = *(const uint4*)(src);
        uint4 s1 = *(const uint4*)(src + 8);
        *(uint4*)(&lds[0][sj * 128 + sw0 * 16]) = s0;
        *(uint4*)(&lds[0][sj * 128 + sw1 * 16]) = s1;
    }
    __syncthreads();

    for (int jt = 0; jt < 8; ++jt) {
        #pragma unroll
        for (int kq = 0; kq < 8; ++kq) {
            const int cb = kq & 1;
            const bool lastp = (jt == 7) && (kq == 7);
            uint4 s0, s1;
            if (!lastp) {   // issue-early: global loads for next tile
                const int njt = (kq == 7) ? jt + 1 : jt;
                const int nkq = (kq + 1) & 7;
                const _Float16* src = Wk16 + ((size_t)(njt * 64 + sj)) * NDIM + nkq * 64 + scp * 16;
                s0 = *(const uint4*)(src);
                s1 = *(const uint4*)(src + 8);
            }
            #pragma unroll
            for (int ktl = 0; ktl < 4; ++ktl) {
                const int kt = kq * 4 + ktl;
                const int ch = (2 * ktl + lhi) ^ (l31 & 7);   // swizzled chunk
                half8 b0 = *(const half8*)(&lds[cb][l31 * 128 + ch * 16]);
                half8 b1 = *(const half8*)(&lds[cb][(32 + l31) * 128 + ch * 16]);
                acc[0] = __builtin_amdgcn_mfma_f32_32x32x16_f16(a[kt], b0, acc[0], 0, 0, 0);
                acc[1] = __builtin_amdgcn_mfma_f32_32x32x16_f16(a[kt], b1, acc[1], 0, 0, 0);
            }
            if (kq == 7) {  // depth complete for this jt: bias + relu + v-weighted reduce
                #pragma unroll
                for (int f = 0; f < 2; ++f) {
                    const int j = jt * 64 + f * 32 + l31;
                    const float bj = bk[j];
                    const float vj = v[j];
                    #pragma unroll
                    for (int r = 0; r < 16; ++r) {
                        float val = acc[f][r] + bj;
                        val = fmaxf(val, 0.f);
                        part[r] = fmaf(val, vj, part[r]);
                        acc[f][r] = 0.f;
                    }
                }
            }
            if (!lastp) {   // write-late into the other buffer
                const int nb = cb ^ 1;
                *(uint4*)(&lds[nb][sj * 128 + sw0 * 16]) = s0;
                *(uint4*)(&lds[nb][sj * 128 + sw1 * 16]) = s1;
            }
            __syncthreads();
        }
    }

    // reduce the 32 j-columns (lanes sharing lhi); C layout: col=lane&31, row=(r&3)+8*(r>>2)+4*lhi
    #pragma unroll
    for (int r = 0; r < 16; ++r) {
        float s = part[r];
        s += __shfl_xor(s, 1);
        s += __shfl_xor(s, 2);
        s += __shfl_xor(s, 4);
        s += __shfl_xor(s, 8);
        s += __shfl_xor(s, 16);
        if (l31 == 0) {
            const int rrow = (r & 3) + 8 * (r >> 2) + 4 * lhi;
            logits[blockIdx.x * BM + wave * 32 + rrow] = s;
        }
    }
}

// ---------------- K3: deterministic per-block exp-sum (256 blocks x 256) ----------------
__global__ void expsum_kernel(const float* __restrict__ logits, float* __restrict__ partial) {
    __shared__ float red[256];
    const int t = threadIdx.x;
    red[t] = expf(logits[blockIdx.x * 256 + t]);
    __syncthreads();
    for (int s = 128; s > 0; s >>= 1) {
        if (t < s) red[t] += red[t + s];
        __syncthreads();
    }
    if (t == 0) partial[blockIdx.x] = red[0];
}

// ---------------- K4: normalize ----------------
__global__ void norm_kernel(const float* __restrict__ logits, const float* __restrict__ partial,
                            float* __restrict__ out) {
    __shared__ float red[256];
    const int t = threadIdx.x;
    red[t] = partial[t];
    __syncthreads();
    for (int s = 128; s > 0; s >>= 1) {
        if (t < s) red[t] += red[t + s];
        __syncthreads();
    }
    const float zinv = 1.0f / red[0];
    const int i = blockIdx.x * 256 + t;
    out[i] = expf(logits[i]) * zinv;
}

extern "C" void kernel_launch(void* const* d_in, const int* in_sizes, int n_in,
                              void* d_out, int out_size, void* d_ws, size_t ws_size,
                              hipStream_t stream) {
    const float* Q    = (const float*)d_in[0];
    const float* Kmat = (const float*)d_in[1];
    const float* Wq   = (const float*)d_in[2];
    const float* bq   = (const float*)d_in[3];
    const float* Wk   = (const float*)d_in[4];
    const float* bk   = (const float*)d_in[5];
    const float* Wout = (const float*)d_in[6];
    float* out = (float*)d_out;

    char* ws = (char*)d_ws;
    _Float16* Wk16 = (_Float16*)(ws);                 // 512*512*2 = 524288 B
    float* v       = (float*)(ws + 524288);           // 2048 B
    float* logits  = (float*)(ws + 526336);           // 262144 B
    float* partial = (float*)(ws + 788480);           // 1024 B

    hipLaunchKernelGGL(qproj_kernel,  dim3(8),   dim3(64),  0, stream, Q, Wq, bq, Wout, v);
    hipLaunchKernelGGL(wkconv_kernel, dim3(256), dim3(256), 0, stream, Wk, Wk16);
    hipLaunchKernelGGL(score_kernel,  dim3(512), dim3(256), 0, stream, Kmat, Wk16, bk, v, logits);
    hipLaunchKernelGGL(expsum_kernel, dim3(256), dim3(256), 0, stream, logits, partial);
    hipLaunchKernelGGL(norm_kernel,   dim3(256), dim3(256), 0, stream, logits, partial, out);
}